// Round 1
// baseline (127.631 us; speedup 1.0000x reference)
//
#include <hip/hip_runtime.h>
#include <math.h>

#define B 8
#define SQ 128
#define SK 128
#define IVD 32
#define DIM 32
#define EV 64
#define H 8
#define NH 128
#define DK 8

// ---------------- Kernel 1: q/k feature MLP + projection ----------------
// grid = B*SQ + B*SK rows, 128 threads/block.
__global__ __launch_bounds__(128) void proj_kernel(
    const float* __restrict__ qv, const float* __restrict__ kv,
    const float* __restrict__ w1, const float* __restrict__ b1,
    const float* __restrict__ w2,
    const float* __restrict__ wq, const float* __restrict__ bq,
    const float* __restrict__ wk, const float* __restrict__ bk,
    float* __restrict__ qout, float* __restrict__ kout)
{
    const int r = blockIdx.x;
    const int tid = threadIdx.x;
    const float* src; const float* wp; const float* bp; float* dst;
    if (r < B * SQ) {
        src = qv + r * IVD; wp = wq; bp = bq; dst = qout + r * EV;
    } else {
        int rr = r - B * SQ;
        src = kv + rr * IVD; wp = wk; bp = bk; dst = kout + rr * EV;
    }
    __shared__ float xs[IVD];
    __shared__ float h1[NH];
    __shared__ float ev[EV];
    if (tid < IVD) xs[tid] = src[tid];
    __syncthreads();
    float acc = b1[tid];
    #pragma unroll
    for (int i = 0; i < IVD; ++i) acc += xs[i] * w1[i * NH + tid];
    h1[tid] = tanhf(acc);
    __syncthreads();
    if (tid < EV) {
        float a = 0.f;
        #pragma unroll 8
        for (int i = 0; i < NH; ++i) a += h1[i] * w2[i * EV + tid];
        ev[tid] = a;
    }
    __syncthreads();
    if (tid < EV) {
        float a = bp[tid];
        #pragma unroll 8
        for (int j = 0; j < EV; ++j) a += ev[j] * wp[j * EV + tid];
        dst[tid] = a;
    }
}

// ---------------- Kernel 2: masked-softmax attention + output GEMV ----------------
// grid = B*SQ blocks (one (b,q) pair each), 256 threads/block.
__global__ __launch_bounds__(256) void attn_kernel(
    const float* __restrict__ qproj, const float* __restrict__ kproj,
    const float* __restrict__ value, const int* __restrict__ mask,
    const float* __restrict__ wo, const float* __restrict__ bo,
    float* __restrict__ y)
{
    const int bq = blockIdx.x;       // b*SQ + q
    const int b = bq >> 7;
    const int tid = threadIdx.x;

    __shared__ float qs[EV];
    __shared__ float sc[H * SK];      // scores, then exp(scores - max)
    __shared__ float hmax[H];
    __shared__ float vm[SK * DIM];    // value slice for this b
    __shared__ float mm[SK * DIM];    // mask (as float) slice for this b
    __shared__ float xr[H * DIM];     // attention output row (256)
    __shared__ float ypart[256];

    if (tid < EV) qs[tid] = qproj[bq * EV + tid];
    for (int idx = tid; idx < SK * DIM; idx += 256) {
        vm[idx] = value[b * SK * DIM + idx];
        mm[idx] = (float)mask[b * SK * DIM + idx];
    }
    __syncthreads();

    // scores: 1024 (h,k) pairs, 4 per thread
    for (int p = tid; p < H * SK; p += 256) {
        const int h = p >> 7, k = p & 127;
        const float* kr = kproj + (b * SK + k) * EV + h * DK;
        float d = 0.f;
        #pragma unroll
        for (int j = 0; j < DK; ++j) d += qs[h * DK + j] * kr[j];
        sc[p] = d * 0.3535533905932738f;   // 1/sqrt(8)
    }
    __syncthreads();

    // per-head max over k (global max over all k; ratio-invariant vs reference)
    if (tid < H) {
        float m = -1e30f;
        for (int k = 0; k < SK; ++k) m = fmaxf(m, sc[tid * SK + k]);
        hmax[tid] = m;
    }
    __syncthreads();
    for (int p = tid; p < H * SK; p += 256) {
        const int h = p >> 7;
        sc[p] = __expf(sc[p] - hmax[h]);
    }
    __syncthreads();

    // per (h,d): masked weighted sum over k. tid -> (h = tid>>5, d = tid&31)
    {
        const int h = tid >> 5, d = tid & 31;
        float num = 0.f, den = 0.f;
        #pragma unroll 4
        for (int k = 0; k < SK; ++k) {
            const float w = sc[h * SK + k] * mm[k * DIM + d];
            num += w * vm[k * DIM + d];
            den += w;
        }
        xr[tid] = num / den;   // x[b, q, h*32+d]
    }
    __syncthreads();

    // y = x @ wo + bo : split the 256-long dot across two halves
    {
        const int n = tid & 127, half = tid >> 7;
        const float* wop = wo + half * 128 * NH;
        const float* xp = xr + half * 128;
        float a = 0.f;
        #pragma unroll 8
        for (int j = 0; j < 128; ++j) a += xp[j] * wop[j * NH + n];
        ypart[tid] = a;
    }
    __syncthreads();
    if (tid < NH) {
        y[bq * NH + tid] = ypart[tid] + ypart[tid + 128] + bo[tid];
    }
}

// ---------------- Kernel 3: impute branch (GEMV + LN + ReLU + GEMV) ----------------
// grid = B*SQ blocks, 128 threads/block.
__global__ __launch_bounds__(128) void impute_kernel(
    const float* __restrict__ imp,
    const float* __restrict__ wd1, const float* __restrict__ bd1,
    const float* __restrict__ ln_g, const float* __restrict__ ln_b,
    const float* __restrict__ wd2, const float* __restrict__ bd2,
    float* __restrict__ out)
{
    const int bs = blockIdx.x;
    const int tid = threadIdx.x;
    __shared__ float xs[IVD / 2];
    __shared__ float h1[NH];
    __shared__ float red[2];

    if (tid < IVD / 2) xs[tid] = imp[bs * (IVD / 2) + tid];
    __syncthreads();
    float acc = bd1[tid];
    #pragma unroll
    for (int i = 0; i < IVD / 2; ++i) acc += xs[i] * wd1[i * NH + tid];

    // mean over the 128 per-thread values (2 waves)
    float s = acc;
    #pragma unroll
    for (int off = 32; off > 0; off >>= 1) s += __shfl_down(s, off, 64);
    if ((tid & 63) == 0) red[tid >> 6] = s;
    __syncthreads();
    const float mean = (red[0] + red[1]) * (1.f / NH);
    const float diff = acc - mean;
    float s2 = diff * diff;
    __syncthreads();   // all reads of red done before overwrite
    #pragma unroll
    for (int off = 32; off > 0; off >>= 1) s2 += __shfl_down(s2, off, 64);
    if ((tid & 63) == 0) red[tid >> 6] = s2;
    __syncthreads();
    const float var = (red[0] + red[1]) * (1.f / NH);   // jnp.var: ddof=0

    const float ln = diff * rsqrtf(var + 1e-5f) * ln_g[tid] + ln_b[tid];
    h1[tid] = fmaxf(ln, 0.f);
    __syncthreads();

    float a = bd2[tid];
    #pragma unroll 8
    for (int j = 0; j < NH; ++j) a += h1[j] * wd2[j * NH + tid];
    out[bs * NH + tid] = a;
}

extern "C" void kernel_launch(void* const* d_in, const int* in_sizes, int n_in,
                              void* d_out, int out_size, void* d_ws, size_t ws_size,
                              hipStream_t stream) {
    const float* query_value = (const float*)d_in[0];
    const float* key_value   = (const float*)d_in[1];
    const float* value       = (const float*)d_in[2];
    const float* impute      = (const float*)d_in[3];
    const int*   emb_mask    = (const int*)d_in[4];
    const float* w1   = (const float*)d_in[5];
    const float* b1   = (const float*)d_in[6];
    const float* w2   = (const float*)d_in[7];
    const float* wq   = (const float*)d_in[8];
    const float* bq   = (const float*)d_in[9];
    const float* wk   = (const float*)d_in[10];
    const float* bk   = (const float*)d_in[11];
    const float* wo   = (const float*)d_in[12];
    const float* bo   = (const float*)d_in[13];
    const float* wd1  = (const float*)d_in[14];
    const float* bd1  = (const float*)d_in[15];
    const float* ln_g = (const float*)d_in[16];
    const float* ln_b = (const float*)d_in[17];
    const float* wd2  = (const float*)d_in[18];
    const float* bd2  = (const float*)d_in[19];

    float* y  = (float*)d_out;                 // (B,SQ,NH)
    float* qd = y + B * SQ * NH;               // (B,SQ,NH)

    float* qproj = (float*)d_ws;               // (B,SQ,EV)
    float* kproj = qproj + B * SQ * EV;        // (B,SK,EV)

    hipLaunchKernelGGL(proj_kernel, dim3(B * (SQ + SK)), dim3(128), 0, stream,
                       query_value, key_value, w1, b1, w2, wq, bq, wk, bk, qproj, kproj);
    hipLaunchKernelGGL(attn_kernel, dim3(B * SQ), dim3(256), 0, stream,
                       qproj, kproj, value, emb_mask, wo, bo, y);
    hipLaunchKernelGGL(impute_kernel, dim3(B * SQ), dim3(128), 0, stream,
                       impute, wd1, bd1, ln_g, ln_b, wd2, bd2, qd);
}

// Round 2
// 117.276 us; speedup vs baseline: 1.0883x; 1.0883x over previous
//
#include <hip/hip_runtime.h>
#include <math.h>

#define B 8
#define SQ 128
#define SK 128
#define IVD 32
#define DIM 32
#define EV 64
#define H 8
#define NH 128
#define DK 8
#define TQ 2
#define PAD 132   // transposed leading dim: SK + 4 floats (16B-aligned rows, spread banks)

// ---------------- Kernel 1: fused q/k projections + impute branch ----------------
// blocks 0 .. 2*B*SQ-1   : q/k feature MLP + projection (one row each)
// blocks 2*B*SQ .. +B*SQ : impute GEMV + LN + ReLU + GEMV (one row each)
__global__ __launch_bounds__(128) void fused1_kernel(
    const float* __restrict__ qv, const float* __restrict__ kv,
    const float* __restrict__ w1, const float* __restrict__ b1,
    const float* __restrict__ w2,
    const float* __restrict__ wq, const float* __restrict__ bqv,
    const float* __restrict__ wk, const float* __restrict__ bkv,
    float* __restrict__ qout, float* __restrict__ kout,
    const float* __restrict__ imp,
    const float* __restrict__ wd1, const float* __restrict__ bd1,
    const float* __restrict__ ln_g, const float* __restrict__ ln_b,
    const float* __restrict__ wd2, const float* __restrict__ bd2,
    float* __restrict__ qd)
{
    const int r = blockIdx.x;
    const int tid = threadIdx.x;

    if (r < 2 * B * SQ) {
        // ---- projection path ----
        __shared__ float xs[IVD];
        __shared__ float h1[NH];
        __shared__ float ev[EV];
        __shared__ float part[128];
        const float* src; const float* wp; const float* bp; float* dst;
        if (r < B * SQ) {
            src = qv + r * IVD; wp = wq; bp = bqv; dst = qout + r * EV;
        } else {
            const int rr = r - B * SQ;
            src = kv + rr * IVD; wp = wk; bp = bkv; dst = kout + rr * EV;
        }
        if (tid < IVD) xs[tid] = src[tid];
        __syncthreads();
        float acc = b1[tid];
        #pragma unroll
        for (int i = 0; i < IVD; ++i) acc += xs[i] * w1[i * NH + tid];
        h1[tid] = tanhf(acc);
        __syncthreads();

        const int o = tid & 63, hf = tid >> 6;
        {   // ev = h1 @ w2 : 64 outputs, dot split in 2 halves across 128 threads
            float a = 0.f;
            const float* w2p = w2 + o;
            #pragma unroll 8
            for (int i = hf * 64; i < hf * 64 + 64; ++i) a += h1[i] * w2p[i * EV];
            part[tid] = a;
        }
        __syncthreads();
        if (tid < EV) ev[tid] = part[tid] + part[tid + 64];
        __syncthreads();
        {   // dst = ev @ wp + bp : 64 outputs, dot split in 2 halves
            float a = 0.f;
            const float* wpp = wp + o;
            #pragma unroll 8
            for (int j = hf * 32; j < hf * 32 + 32; ++j) a += ev[j] * wpp[j * EV];
            part[tid] = a;
        }
        __syncthreads();
        if (tid < EV) dst[tid] = part[tid] + part[tid + 64] + bp[tid];
    } else {
        // ---- impute path ----
        const int bs = r - 2 * B * SQ;
        __shared__ float xs2[IVD / 2];
        __shared__ float h1b[NH];
        __shared__ float red[2];

        if (tid < IVD / 2) xs2[tid] = imp[bs * (IVD / 2) + tid];
        __syncthreads();
        float acc = bd1[tid];
        #pragma unroll
        for (int i = 0; i < IVD / 2; ++i) acc += xs2[i] * wd1[i * NH + tid];

        float s = acc;
        #pragma unroll
        for (int off = 32; off > 0; off >>= 1) s += __shfl_down(s, off, 64);
        if ((tid & 63) == 0) red[tid >> 6] = s;
        __syncthreads();
        const float mean = (red[0] + red[1]) * (1.f / NH);
        const float diff = acc - mean;
        float s2 = diff * diff;
        __syncthreads();
        #pragma unroll
        for (int off = 32; off > 0; off >>= 1) s2 += __shfl_down(s2, off, 64);
        if ((tid & 63) == 0) red[tid >> 6] = s2;
        __syncthreads();
        const float var = (red[0] + red[1]) * (1.f / NH);

        const float ln = diff * rsqrtf(var + 1e-5f) * ln_g[tid] + ln_b[tid];
        h1b[tid] = fmaxf(ln, 0.f);
        __syncthreads();

        float a = bd2[tid];
        #pragma unroll 8
        for (int j = 0; j < NH; ++j) a += h1b[j] * wd2[j * NH + tid];
        qd[bs * NH + tid] = a;
    }
}

// ---------------- Kernel 2: masked-softmax attention + output GEMV ----------------
// grid = B * SQ/TQ blocks; each handles TQ=2 q rows of one batch. 256 threads.
__global__ __launch_bounds__(256) void attn_kernel(
    const float* __restrict__ qproj, const float* __restrict__ kproj,
    const float* __restrict__ value, const int* __restrict__ mask,
    const float* __restrict__ wo, const float* __restrict__ bo,
    float* __restrict__ y)
{
    const int blk = blockIdx.x;
    const int b = blk >> 6;               // 64 blocks per batch (SQ/TQ)
    const int q0 = (blk & 63) * TQ;
    const int tid = threadIdx.x;

    __shared__ __align__(16) float qs[TQ * EV];        // 2 q rows
    __shared__ __align__(16) float sc[TQ * H * SK];    // scores -> exp'd scores
    __shared__ __align__(16) float mvt[DIM * PAD];     // (mask*value)^T  [d][k]
    __shared__ __align__(16) float mmt[DIM * PAD];     // mask^T          [d][k]
    __shared__ __align__(16) float xr[TQ * H * DIM];   // attn out rows (2 x 256)
    __shared__ __align__(16) float ypart[2 * TQ * NH]; // half-dots
    __shared__ float hmax[TQ * H];

    if (tid < TQ * EV) qs[tid] = qproj[(b * SQ + q0) * EV + tid];
    for (int idx = tid; idx < SK * DIM; idx += 256) {
        const int k = idx >> 5, d = idx & 31;
        const float v = value[b * SK * DIM + idx];
        const float m = (float)mask[b * SK * DIM + idx];
        mvt[d * PAD + k] = v * m;
        mmt[d * PAD + k] = m;
    }
    __syncthreads();

    // scores: TQ*H*SK = 2048 entries, 8 per thread
    #pragma unroll
    for (int i = 0; i < (TQ * H * SK) / 256; ++i) {
        const int p = tid + i * 256;
        const int q = p >> 10, rem = p & 1023, h = rem >> 7, k = rem & 127;
        const float* kr = kproj + (b * SK + k) * EV + h * DK;
        const float* qq = qs + q * EV + h * DK;
        float dsum = 0.f;
        #pragma unroll
        for (int j = 0; j < DK; ++j) dsum += qq[j] * kr[j];
        sc[p] = dsum * 0.3535533905932738f;   // 1/sqrt(DK)
    }
    __syncthreads();

    // per (q,h) max over k: 16 groups x 16 threads, shuffle-reduce width 16
    {
        const int grp = tid >> 4, ln = tid & 15;
        float m = -1e30f;
        #pragma unroll
        for (int j = 0; j < 8; ++j) m = fmaxf(m, sc[(grp << 7) + ln * 8 + j]);
        #pragma unroll
        for (int off = 8; off; off >>= 1) m = fmaxf(m, __shfl_down(m, off, 16));
        if (ln == 0) hmax[grp] = m;
    }
    __syncthreads();
    {
        const int grp = tid >> 4, ln = tid & 15;
        const float hm = hmax[grp];
        #pragma unroll
        for (int j = 0; j < 8; ++j) {
            const int idx = (grp << 7) + ln * 8 + j;
            sc[idx] = __expf(sc[idx] - hm);
        }
    }
    __syncthreads();

    // weighted masked sums: thread owns (h,d); k-loop vectorized float4
    {
        const int h = tid >> 5, d = tid & 31;
        const float4* vp = (const float4*)&mvt[d * PAD];
        const float4* mp = (const float4*)&mmt[d * PAD];
        #pragma unroll
        for (int q = 0; q < TQ; ++q) {
            const float4* sp = (const float4*)&sc[(q * H + h) * SK];
            float num = 0.f, den = 0.f;
            #pragma unroll 8
            for (int k4 = 0; k4 < SK / 4; ++k4) {
                const float4 s = sp[k4], v = vp[k4], m = mp[k4];
                num += s.x * v.x + s.y * v.y + s.z * v.z + s.w * v.w;
                den += s.x * m.x + s.y * m.y + s.z * m.z + s.w * m.w;
            }
            xr[q * (H * DIM) + h * DIM + d] = num / den;
        }
    }
    __syncthreads();

    // y = x @ wo + bo : 256-dot split in halves, wo load shared across TQ rows
    {
        const int n = tid & 127, half = tid >> 7;
        const float* wop = wo + half * 128 * NH + n;
        const float* x0 = xr + half * 128;
        const float* x1 = xr + (H * DIM) + half * 128;
        float a0 = 0.f, a1 = 0.f;
        #pragma unroll 4
        for (int j = 0; j < 128; ++j) {
            const float w = wop[j * NH];
            a0 += w * x0[j];
            a1 += w * x1[j];
        }
        ypart[half * (TQ * NH) + 0 * NH + n] = a0;
        ypart[half * (TQ * NH) + 1 * NH + n] = a1;
    }
    __syncthreads();
    {
        const int q = tid >> 7, n = tid & 127;
        y[(b * SQ + q0 + q) * NH + n] =
            ypart[q * NH + n] + ypart[TQ * NH + q * NH + n] + bo[n];
    }
}

extern "C" void kernel_launch(void* const* d_in, const int* in_sizes, int n_in,
                              void* d_out, int out_size, void* d_ws, size_t ws_size,
                              hipStream_t stream) {
    const float* query_value = (const float*)d_in[0];
    const float* key_value   = (const float*)d_in[1];
    const float* value       = (const float*)d_in[2];
    const float* impute      = (const float*)d_in[3];
    const int*   emb_mask    = (const int*)d_in[4];
    const float* w1   = (const float*)d_in[5];
    const float* b1   = (const float*)d_in[6];
    const float* w2   = (const float*)d_in[7];
    const float* wq   = (const float*)d_in[8];
    const float* bq   = (const float*)d_in[9];
    const float* wk   = (const float*)d_in[10];
    const float* bk   = (const float*)d_in[11];
    const float* wo   = (const float*)d_in[12];
    const float* bo   = (const float*)d_in[13];
    const float* wd1  = (const float*)d_in[14];
    const float* bd1  = (const float*)d_in[15];
    const float* ln_g = (const float*)d_in[16];
    const float* ln_b = (const float*)d_in[17];
    const float* wd2  = (const float*)d_in[18];
    const float* bd2  = (const float*)d_in[19];

    float* y  = (float*)d_out;                 // (B,SQ,NH)
    float* qd = y + B * SQ * NH;               // (B,SQ,NH)

    float* qproj = (float*)d_ws;               // (B,SQ,EV)
    float* kproj = qproj + B * SQ * EV;        // (B,SK,EV)

    hipLaunchKernelGGL(fused1_kernel, dim3(3 * B * SQ), dim3(128), 0, stream,
                       query_value, key_value, w1, b1, w2, wq, bq, wk, bk,
                       qproj, kproj,
                       impute, wd1, bd1, ln_g, ln_b, wd2, bd2, qd);
    hipLaunchKernelGGL(attn_kernel, dim3(B * SQ / TQ), dim3(256), 0, stream,
                       qproj, kproj, value, emb_mask, wo, bo, y);
}

// Round 3
// 114.821 us; speedup vs baseline: 1.1116x; 1.0214x over previous
//
#include <hip/hip_runtime.h>
#include <math.h>

#define B 8
#define SQ 128
#define SK 128
#define IVD 32
#define DIM 32
#define EV 64
#define H 8
#define NH 128
#define DK 8
#define TQ 2
#define KG 8      // k-groups in weighted-sum phase (16 k each)
#define PAD 132   // transposed leading dim: SK + 4 floats

__device__ __forceinline__ float fast_tanh(float x) {
    const float xc = fminf(fmaxf(x, -10.f), 10.f);
    const float t = __expf(2.f * xc);
    return (t - 1.f) / (t + 1.f);
}

// ---------------- Kernel 1: q/k projections + impute, 2 rows per block ----------------
// blocks [0,512)    : q-row pairs
// blocks [512,1024) : k-row pairs
// blocks [1024,1536): impute-row pairs
__global__ __launch_bounds__(128) void fused1_kernel(
    const float* __restrict__ qv, const float* __restrict__ kv,
    const float* __restrict__ w1, const float* __restrict__ b1,
    const float* __restrict__ w2,
    const float* __restrict__ wq, const float* __restrict__ bqv,
    const float* __restrict__ wk, const float* __restrict__ bkv,
    float* __restrict__ qout, float* __restrict__ kout,
    const float* __restrict__ imp,
    const float* __restrict__ wd1, const float* __restrict__ bd1,
    const float* __restrict__ ln_g, const float* __restrict__ ln_b,
    const float* __restrict__ wd2, const float* __restrict__ bd2,
    float* __restrict__ qd)
{
    const int r = blockIdx.x;
    const int tid = threadIdx.x;

    if (r < 1024) {
        // ---- projection path, rows row0, row0+1 ----
        __shared__ float xs[2][IVD];
        __shared__ float h1[2][NH];
        __shared__ float ev[2][EV];
        __shared__ float part[2][128];
        const float* src; const float* wp; const float* bp; float* dst;
        int row0;
        if (r < 512) { row0 = r * 2;         src = qv; wp = wq; bp = bqv; dst = qout; }
        else         { row0 = (r - 512) * 2; src = kv; wp = wk; bp = bkv; dst = kout; }

        if (tid < 2 * IVD) xs[tid >> 5][tid & 31] = src[row0 * IVD + tid];
        __syncthreads();

        // GEMV1: h1 = tanh(x @ w1 + b1), 128 outputs x 2 rows, shared weight load
        {
            float a0 = b1[tid], a1 = a0;
            #pragma unroll
            for (int i = 0; i < IVD; ++i) {
                const float w = w1[i * NH + tid];
                a0 += xs[0][i] * w; a1 += xs[1][i] * w;
            }
            h1[0][tid] = fast_tanh(a0);
            h1[1][tid] = fast_tanh(a1);
        }
        __syncthreads();

        const int o = tid & 63, hf = tid >> 6;
        // GEMV2: ev = h1 @ w2 (64 outs, dot split in 2 halves, 2 rows share w)
        {
            float c0 = 0.f, c1 = 0.f;
            #pragma unroll 8
            for (int i = hf * 64; i < hf * 64 + 64; ++i) {
                const float w = w2[i * EV + o];
                c0 += h1[0][i] * w; c1 += h1[1][i] * w;
            }
            part[0][tid] = c0; part[1][tid] = c1;
        }
        __syncthreads();
        {
            const int row = tid >> 6, oo = tid & 63;
            ev[row][oo] = part[row][oo] + part[row][oo + 64];
        }
        __syncthreads();
        // GEMV3: dst = ev @ wp + bp
        {
            float c0 = 0.f, c1 = 0.f;
            #pragma unroll 8
            for (int j = hf * 32; j < hf * 32 + 32; ++j) {
                const float w = wp[j * EV + o];
                c0 += ev[0][j] * w; c1 += ev[1][j] * w;
            }
            part[0][tid] = c0; part[1][tid] = c1;
        }
        __syncthreads();
        {
            const int row = tid >> 6, oo = tid & 63;
            dst[(row0 + row) * EV + oo] = part[row][oo] + part[row][oo + 64] + bp[oo];
        }
    } else {
        // ---- impute path, rows bs0, bs0+1 ----
        const int bs0 = (r - 1024) * 2;
        __shared__ float xs2[2][IVD / 2];
        __shared__ float h1b[2][NH];
        __shared__ float red[2][2];

        if (tid < IVD) xs2[tid >> 4][tid & 15] = imp[bs0 * (IVD / 2) + tid];
        __syncthreads();
        float a0 = bd1[tid], a1 = a0;
        #pragma unroll
        for (int i = 0; i < IVD / 2; ++i) {
            const float w = wd1[i * NH + tid];
            a0 += xs2[0][i] * w; a1 += xs2[1][i] * w;
        }

        float s0 = a0, s1 = a1;
        #pragma unroll
        for (int off = 32; off > 0; off >>= 1) {
            s0 += __shfl_down(s0, off, 64);
            s1 += __shfl_down(s1, off, 64);
        }
        if ((tid & 63) == 0) { red[0][tid >> 6] = s0; red[1][tid >> 6] = s1; }
        __syncthreads();
        const float mu0 = (red[0][0] + red[0][1]) * (1.f / NH);
        const float mu1 = (red[1][0] + red[1][1]) * (1.f / NH);
        const float d0 = a0 - mu0, d1 = a1 - mu1;
        float t0 = d0 * d0, t1 = d1 * d1;
        __syncthreads();
        #pragma unroll
        for (int off = 32; off > 0; off >>= 1) {
            t0 += __shfl_down(t0, off, 64);
            t1 += __shfl_down(t1, off, 64);
        }
        if ((tid & 63) == 0) { red[0][tid >> 6] = t0; red[1][tid >> 6] = t1; }
        __syncthreads();
        const float v0 = (red[0][0] + red[0][1]) * (1.f / NH);
        const float v1 = (red[1][0] + red[1][1]) * (1.f / NH);

        const float g = ln_g[tid], bb = ln_b[tid];
        h1b[0][tid] = fmaxf(d0 * rsqrtf(v0 + 1e-5f) * g + bb, 0.f);
        h1b[1][tid] = fmaxf(d1 * rsqrtf(v1 + 1e-5f) * g + bb, 0.f);
        __syncthreads();

        float c0 = bd2[tid], c1 = c0;
        #pragma unroll 8
        for (int j = 0; j < NH; ++j) {
            const float w = wd2[j * NH + tid];
            c0 += h1b[0][j] * w; c1 += h1b[1][j] * w;
        }
        qd[bs0 * NH + tid] = c0;
        qd[(bs0 + 1) * NH + tid] = c1;
    }
}

// ---------------- Kernel 2: masked-softmax attention + output GEMV ----------------
// grid = B * SQ/TQ blocks; each handles TQ=2 q rows of one batch. 256 threads.
__global__ __launch_bounds__(256) void attn_kernel(
    const float* __restrict__ qproj, const float* __restrict__ kproj,
    const float* __restrict__ value, const int* __restrict__ mask,
    const float* __restrict__ wo, const float* __restrict__ bo,
    float* __restrict__ y)
{
    const int blk = blockIdx.x;
    const int b = blk >> 6;               // 64 blocks per batch (SQ/TQ)
    const int q0 = (blk & 63) * TQ;
    const int tid = threadIdx.x;

    __shared__ __align__(16) float qs[TQ * EV];        // pre-scaled q rows
    __shared__ __align__(16) float sc[TQ * H * SK];    // exp'd scores
    __shared__ __align__(16) float mvt[DIM * PAD];     // (mask*value)^T [d][k]
    __shared__ __align__(16) float mmt[DIM * PAD];     // mask^T         [d][k]
    __shared__ __align__(16) float2 part[H * KG * DIM];// per-q partials (16 KB)
    __shared__ __align__(16) float xr[TQ * H * DIM];   // attn out rows
    __shared__ __align__(16) float ypart[2 * TQ * NH];

    if (tid < TQ * EV) qs[tid] = qproj[(b * SQ + q0) * EV + tid] * 0.3535533905932738f;
    for (int idx = tid; idx < SK * DIM; idx += 256) {
        const int k = idx >> 5, d = idx & 31;
        const float v = value[b * SK * DIM + idx];
        const float m = (float)mask[b * SK * DIM + idx];
        mvt[d * PAD + k] = v * m;
        mmt[d * PAD + k] = m;
    }
    __syncthreads();

    // scores -> exp directly (no max subtraction: |s| bounded ~O(10), f32-safe,
    // ratios identical to reference softmax; masked logits' weight is exactly 0
    // in the reference too)
    #pragma unroll
    for (int i = 0; i < (TQ * H * SK) / 256; ++i) {
        const int p = tid + i * 256;
        const int q = p >> 10, rem = p & 1023, h = rem >> 7, k = rem & 127;
        const float4* kr = (const float4*)(kproj + (b * SK + k) * EV + h * DK);
        const float4* qq = (const float4*)(qs + q * EV + h * DK);
        const float4 k0 = kr[0], k1 = kr[1], qa = qq[0], qb = qq[1];
        const float s = qa.x * k0.x + qa.y * k0.y + qa.z * k0.z + qa.w * k0.w
                      + qb.x * k1.x + qb.y * k1.y + qb.z * k1.z + qb.w * k1.w;
        sc[p] = __expf(s);
    }
    __syncthreads();

    // weighted masked sums: thread owns (d, kg) -> value/mask slice in registers
    {
        const int d = tid & 31, kg = tid >> 5;
        float4 vv[4], mq[4];
        const float4* vp = (const float4*)&mvt[d * PAD + kg * 16];
        const float4* mp = (const float4*)&mmt[d * PAD + kg * 16];
        #pragma unroll
        for (int j = 0; j < 4; ++j) { vv[j] = vp[j]; mq[j] = mp[j]; }

        #pragma unroll
        for (int q = 0; q < TQ; ++q) {
            #pragma unroll
            for (int h = 0; h < H; ++h) {
                const float4* sp = (const float4*)&sc[(q * H + h) * SK + kg * 16];
                float num = 0.f, den = 0.f;
                #pragma unroll
                for (int j = 0; j < 4; ++j) {
                    const float4 s = sp[j];
                    num += s.x * vv[j].x + s.y * vv[j].y + s.z * vv[j].z + s.w * vv[j].w;
                    den += s.x * mq[j].x + s.y * mq[j].y + s.z * mq[j].z + s.w * mq[j].w;
                }
                part[(h * KG + kg) * DIM + d] = make_float2(num, den);
            }
            __syncthreads();
            {   // reduce 8 k-groups; thread -> (h = tid>>5, d = tid&31)
                const int h = tid >> 5;
                float num = 0.f, den = 0.f;
                #pragma unroll
                for (int g = 0; g < KG; ++g) {
                    const float2 p2 = part[(h * KG + g) * DIM + d];
                    num += p2.x; den += p2.y;
                }
                xr[q * (H * DIM) + tid] = num / den;
            }
            __syncthreads();
        }
    }

    // y = x @ wo + bo : 256-dot split in halves, wo load shared across TQ rows
    {
        const int n = tid & 127, half = tid >> 7;
        const float* wop = wo + half * 128 * NH + n;
        const float* x0 = xr + half * 128;
        const float* x1 = xr + (H * DIM) + half * 128;
        float a0 = 0.f, a1 = 0.f;
        #pragma unroll 4
        for (int j = 0; j < 128; ++j) {
            const float w = wop[j * NH];
            a0 += w * x0[j];
            a1 += w * x1[j];
        }
        ypart[half * (TQ * NH) + 0 * NH + n] = a0;
        ypart[half * (TQ * NH) + 1 * NH + n] = a1;
    }
    __syncthreads();
    {
        const int q = tid >> 7, n = tid & 127;
        y[(b * SQ + q0 + q) * NH + n] =
            ypart[q * NH + n] + ypart[TQ * NH + q * NH + n] + bo[n];
    }
}

extern "C" void kernel_launch(void* const* d_in, const int* in_sizes, int n_in,
                              void* d_out, int out_size, void* d_ws, size_t ws_size,
                              hipStream_t stream) {
    const float* query_value = (const float*)d_in[0];
    const float* key_value   = (const float*)d_in[1];
    const float* value       = (const float*)d_in[2];
    const float* impute      = (const float*)d_in[3];
    const int*   emb_mask    = (const int*)d_in[4];
    const float* w1   = (const float*)d_in[5];
    const float* b1   = (const float*)d_in[6];
    const float* w2   = (const float*)d_in[7];
    const float* wq   = (const float*)d_in[8];
    const float* bq   = (const float*)d_in[9];
    const float* wk   = (const float*)d_in[10];
    const float* bk   = (const float*)d_in[11];
    const float* wo   = (const float*)d_in[12];
    const float* bo   = (const float*)d_in[13];
    const float* wd1  = (const float*)d_in[14];
    const float* bd1  = (const float*)d_in[15];
    const float* ln_g = (const float*)d_in[16];
    const float* ln_b = (const float*)d_in[17];
    const float* wd2  = (const float*)d_in[18];
    const float* bd2  = (const float*)d_in[19];

    float* y  = (float*)d_out;                 // (B,SQ,NH)
    float* qd = y + B * SQ * NH;               // (B,SQ,NH)

    float* qproj = (float*)d_ws;               // (B,SQ,EV)
    float* kproj = qproj + B * SQ * EV;        // (B,SK,EV)

    hipLaunchKernelGGL(fused1_kernel, dim3(1536), dim3(128), 0, stream,
                       query_value, key_value, w1, b1, w2, wq, bq, wk, bk,
                       qproj, kproj,
                       impute, wd1, bd1, ln_g, ln_b, wd2, bd2, qd);
    hipLaunchKernelGGL(attn_kernel, dim3(B * SQ / TQ), dim3(256), 0, stream,
                       qproj, kproj, value, emb_mask, wo, bo, y);
}